// Round 10
// baseline (843.789 us; speedup 1.0000x reference)
//
#include <hip/hip_runtime.h>

// MoE router: x(4,8192,4096) fp32, W(64,4096) fp32
// logits = x @ W^T ; softmax(64) ; top-2 ; renorm
// Outputs concat: probs (32768*64) | indices-as-float (32768*2) | weights (32768*2)
//
// Structure: 512 blocks x 256 thr (4 waves). Block = 64 tokens; each wave owns a
// 1024-wide K-slice (K-split x4), LDS cross-wave reduce at the end.
// x staged transposed in LDS ([k][token] pad-68) with T14 cross-iteration
// prefetch (loads for tile it+1 issued before tile it's FMA block).
// W read straight from global (L1/L2-resident, 2KB hot per K-chunk) -- keeps
// the LDS pipe at ~25% (FMA-loop ds_reads are 8-lane broadcasts).
// Expected regime: fp32-VALU-bound (~109us floor; HBM floor 83us; no fp32 MFMA).

#define TOKENS 32768
#define DIM    4096
#define NEXP   64
#define BM     64      // tokens per block
#define NSLICE 4       // K-split across the 4 waves of a block
#define BK     32      // k per slice per step
#define KSTEPS 32      // (DIM/NSLICE)/BK

// ---- W pre-transpose: Wt[k][e] = W[e][k], 4096x64 --------------------------
__global__ void wt_transpose(const float* __restrict__ W, float* __restrict__ Wt) {
    int idx = blockIdx.x * 256 + threadIdx.x;   // 262144 elements, grid 1024
    int k = idx >> 6, e = idx & 63;
    Wt[idx] = W[e * DIM + k];
}

// ---- main fused kernel -----------------------------------------------------
// USE_WT: true -> Wm is the pre-transposed Wt[k][e] (fast path, needs 1MiB ws)
//         false -> Wm is raw W[e][k] (correct fallback if ws too small)
template <bool USE_WT>
__launch_bounds__(256, 2)
__global__ void router_kernel(const float* __restrict__ x,
                              const float* __restrict__ Wm,
                              float* __restrict__ outP,
                              float* __restrict__ outI,
                              float* __restrict__ outW) {
    // xs: [slice][k][token(padded 68)] transposed x tile; 4*32*68*4 = 34816 B.
    // Re-used as lg[64][68] for the cross-wave logit reduce.
    __shared__ __align__(16) float xs[NSLICE][BK][68];

    const int t    = threadIdx.x;
    const int wv   = t >> 6;       // wave 0..3 -> K slice
    const int lane = t & 63;
    const int tx   = lane & 7;     // expert octet
    const int ty   = lane >> 3;    // token octet 0..7
    const int m0   = blockIdx.x * BM;

    float acc[8][8];
#pragma unroll
    for (int i = 0; i < 8; ++i)
#pragma unroll
        for (int j = 0; j < 8; ++j) acc[i][j] = 0.f;

    // x staging assignment: 4 lanes per token row, 16B quads
    const int sm_ = t >> 2;              // token row 0..63
    const int skq = (t & 3) << 2;        // k quad 0,4,8,12
    const float* xgb = x + (size_t)(m0 + sm_) * DIM + skq;

    const float* xsl = &xs[wv][0][0];
    const float* wgl = USE_WT ? (Wm + (wv * 1024) * 64 + 8 * tx) : nullptr;

    // ---- prologue: load tile 0 into registers -----------------------------
    float4 vbuf[NSLICE][2];
#pragma unroll
    for (int p = 0; p < NSLICE; ++p)
#pragma unroll
        for (int h = 0; h < 2; ++h)
            vbuf[p][h] = *(const float4*)(xgb + p * 1024 + h * 16);

    for (int it = 0; it < KSTEPS; ++it) {
        const int kb = it * BK;
        // ---- write current tile's registers into LDS (transposed) --------
#pragma unroll
        for (int p = 0; p < NSLICE; ++p)
#pragma unroll
            for (int h = 0; h < 2; ++h) {
                const float4 v = vbuf[p][h];
                float* dst = &xs[p][h * 16][0];
                dst[(skq + 0) * 68 + sm_] = v.x;
                dst[(skq + 1) * 68 + sm_] = v.y;
                dst[(skq + 2) * 68 + sm_] = v.z;
                dst[(skq + 3) * 68 + sm_] = v.w;
            }
        __syncthreads();

        // ---- T14 split: issue NEXT tile's global loads before this FMA ----
        if (it + 1 < KSTEPS) {
            const int kb2 = (it + 1) * BK;
#pragma unroll
            for (int p = 0; p < NSLICE; ++p)
#pragma unroll
                for (int h = 0; h < 2; ++h)
                    vbuf[p][h] = *(const float4*)(xgb + p * 1024 + kb2 + h * 16);
        }

        // ---- FMA block on tile it (x from LDS broadcast, W from L1) -------
#pragma unroll
        for (int k = 0; k < BK; ++k) {
            const float4 xa = *(const float4*)(xsl + k * 68 + 8 * ty);
            const float4 xb = *(const float4*)(xsl + k * 68 + 8 * ty + 4);
            const float xv[8] = {xa.x, xa.y, xa.z, xa.w, xb.x, xb.y, xb.z, xb.w};
            float wvv[8];
            if constexpr (USE_WT) {
                const float* wk = wgl + (kb + k) * 64;
                const float4 wa = *(const float4*)(wk);       // L1-hot, contiguous
                const float4 wb = *(const float4*)(wk + 4);
                wvv[0]=wa.x; wvv[1]=wa.y; wvv[2]=wa.z; wvv[3]=wa.w;
                wvv[4]=wb.x; wvv[5]=wb.y; wvv[6]=wb.z; wvv[7]=wb.w;
            } else {
                const int kglob = wv * 1024 + kb + k;
#pragma unroll
                for (int j = 0; j < 8; ++j)
                    wvv[j] = Wm[(size_t)(8 * tx + j) * DIM + kglob];  // L2-hot scalar
            }
#pragma unroll
            for (int i = 0; i < 8; ++i)
#pragma unroll
                for (int j = 0; j < 8; ++j)
                    acc[i][j] = fmaf(xv[i], wvv[j], acc[i][j]);
        }
        __syncthreads();
    }

    // ---- reduce the 4 waves' K-partials into lg[64][68] (aliases xs) ------
    // Serialized w-rounds; float4 R/M/W (8-way bank conflict tolerated: once/block)
    float* lg = &xs[0][0][0];
#pragma unroll
    for (int w = 0; w < NSLICE; ++w) {
        if (wv == w) {
#pragma unroll
            for (int i = 0; i < 8; ++i) {
                float* row = lg + (8 * ty + i) * 68 + 8 * tx;
                if (w == 0) {
                    *(float4*)(row)     = make_float4(acc[i][0], acc[i][1], acc[i][2], acc[i][3]);
                    *(float4*)(row + 4) = make_float4(acc[i][4], acc[i][5], acc[i][6], acc[i][7]);
                } else {
                    float4 a = *(const float4*)(row);
                    float4 b = *(const float4*)(row + 4);
                    a.x += acc[i][0]; a.y += acc[i][1]; a.z += acc[i][2]; a.w += acc[i][3];
                    b.x += acc[i][4]; b.y += acc[i][5]; b.z += acc[i][6]; b.w += acc[i][7];
                    *(float4*)(row)     = a;
                    *(float4*)(row + 4) = b;
                }
            }
        }
        __syncthreads();
    }

    // ---- epilogue: 4 threads per token, 16 experts each -------------------
    const int tok = t >> 2;
    const int q   = t & 3;
    float v[16];
    const float* lrow = lg + tok * 68 + q * 16;
#pragma unroll
    for (int u = 0; u < 4; ++u) {
        const float4 vv = *(const float4*)(lrow + 4 * u);
        v[4*u+0] = vv.x; v[4*u+1] = vv.y; v[4*u+2] = vv.z; v[4*u+3] = vv.w;
    }
    // group max over 64 (4-lane group, shfl_xor stays in-wave)
    float mx = v[0];
#pragma unroll
    for (int j = 1; j < 16; ++j) mx = fmaxf(mx, v[j]);
    mx = fmaxf(mx, __shfl_xor(mx, 1));
    mx = fmaxf(mx, __shfl_xor(mx, 2));
    // exp + group sum (expf = 1-ulp OCML path, matches XLA's exp lowering)
    float e[16]; float s = 0.f;
#pragma unroll
    for (int j = 0; j < 16; ++j) { e[j] = expf(v[j] - mx); s += e[j]; }
    s += __shfl_xor(s, 1);
    s += __shfl_xor(s, 2);
    const float inv = 1.0f / s;
    const int gtok = m0 + tok;
    float* op = outP + (size_t)gtok * 64 + q * 16;
#pragma unroll
    for (int u = 0; u < 4; ++u) {
        float4 pv = make_float4(e[4*u]*inv, e[4*u+1]*inv, e[4*u+2]*inv, e[4*u+3]*inv);
        *(float4*)(op + 4*u) = pv;
    }
    // local top-2 on logits (ascending j => ties keep lower index, jax-style)
    float b1 = -1e30f, b2 = -1e30f; int i1 = 0, i2 = 0;
#pragma unroll
    for (int j = 0; j < 16; ++j) {
        const int ei = q * 16 + j;
        if (v[j] > b1)      { b2 = b1; i2 = i1; b1 = v[j]; i1 = ei; }
        else if (v[j] > b2) { b2 = v[j]; i2 = ei; }
    }
    // merge across the 4-lane group (second = max(loser-first, winner-second))
#pragma unroll
    for (int d = 1; d < 4; d <<= 1) {
        float o1 = __shfl_xor(b1, d); int oi1 = __shfl_xor(i1, d);
        float o2 = __shfl_xor(b2, d); int oi2 = __shfl_xor(i2, d);
        bool keep = (b1 > o1) || (b1 == o1 && i1 < oi1);
        float n1 = keep ? b1 : o1;  int ni1 = keep ? i1 : oi1;
        float c2 = keep ? o1 : b1;  int ci2 = keep ? oi1 : i1;
        float c3 = keep ? b2 : o2;  int ci3 = keep ? i2  : oi2;
        bool k2 = (c2 > c3) || (c2 == c3 && ci2 < ci3);
        b1 = n1; i1 = ni1;
        b2 = k2 ? c2 : c3; i2 = k2 ? ci2 : ci3;
    }
    if (q == 0) {
        const float e1 = expf(b1 - mx), e2 = expf(b2 - mx);
        const float r = 1.0f / (e1 + e2);        // softmax denom cancels in renorm
        outI[gtok * 2]     = (float)i1;
        outI[gtok * 2 + 1] = (float)i2;
        outW[gtok * 2]     = e1 * r;
        outW[gtok * 2 + 1] = e2 * r;
    }
}

extern "C" void kernel_launch(void* const* d_in, const int* in_sizes, int n_in,
                              void* d_out, int out_size, void* d_ws, size_t ws_size,
                              hipStream_t stream) {
    const float* x = (const float*)d_in[0];
    const float* W = (const float*)d_in[1];
    float* out  = (float*)d_out;
    float* outP = out;                                // 32768*64
    float* outI = out + 32768 * 64;                   // 32768*2 (indices as float)
    float* outW = outI + 32768 * 2;                   // 32768*2

    if (ws_size >= (size_t)DIM * NEXP * sizeof(float)) {
        float* Wt = (float*)d_ws;                     // 1 MiB scratch
        wt_transpose<<<1024, 256, 0, stream>>>(W, Wt);
        router_kernel<true><<<512, 256, 0, stream>>>(x, Wt, outP, outI, outW);
    } else {
        router_kernel<false><<<512, 256, 0, stream>>>(x, W, outP, outI, outW);
    }
}